// Round 9
// baseline (257.548 us; speedup 1.0000x reference)
//
#include <hip/hip_runtime.h>

// ---------------------------------------------------------------------------
// GraphSAGE (max-pool SAGE x2 + edge heads), fp32 in/out, fp16 intermediates.
// Identity 1: relu((neigh*scale) @ W.T + b) = relu(scale*(neigh@W.T) + b)
//   -> pool matmul per-NODE (50k) not per-EDGE (1.6M).
// Identity 2: max seeded at 0 == relu'd max with empty->0.
// Round 9: R8 showed fin kernels at VGPR=76 -> compiler REMATERIALIZED the
//   per-lane weight loads inside the node loop (stride-512B -> 64 lines per
//   re-load; 46 us, VALU 22%, issue-bound). Fix: pin weights in VGPRs via
//   opaque asm volatile("" : "+v") (LLVM can't remat inline-asm results) and
//   split the serial FMA chain into 2-4 independent accumulators.
// ---------------------------------------------------------------------------

typedef _Float16 h16;

#define NBMAX 1600          // buckets of 32 nodes: ceil(50000/32)=1563
#define NFB   128           // blocks for hist/binfill
#define PIN(v) asm volatile("" : "+v"(v))

union HU { unsigned u; h16 h[2]; };

// Z16 = X @ W.T   (X:[n,64] fp32 or fp16, W:[64,64] row-major, Z:[n,64] fp16)
template <bool XHALF>
__global__ __launch_bounds__(256, 4)
void mm64_kernel(const void* __restrict__ Xv,
                 const float* __restrict__ W,
                 h16* __restrict__ Z, int n) {
    const int lane = threadIdx.x & 63;
    int wave = (int)((blockIdx.x * blockDim.x + threadIdx.x) >> 6);
    const int nwaves = (int)((gridDim.x * blockDim.x) >> 6);
    float w[64];
#pragma unroll
    for (int k = 0; k < 64; ++k) w[k] = W[lane * 64 + k];
#pragma unroll
    for (int k = 0; k < 64; ++k) PIN(w[k]);   // force register residency
    for (int node = wave; node < n; node += nwaves) {
        const int nu = __builtin_amdgcn_readfirstlane(node);
        float a0 = 0.f, a1 = 0.f;
        if constexpr (XHALF) {
            const unsigned* xr = (const unsigned*)((const h16*)Xv + (size_t)nu * 64);
#pragma unroll
            for (int k2 = 0; k2 < 32; ++k2) {
                HU cv; cv.u = xr[k2];
                a0 = fmaf(w[2 * k2], (float)cv.h[0], a0);
                a1 = fmaf(w[2 * k2 + 1], (float)cv.h[1], a1);
            }
        } else {
            const float* xr = (const float*)Xv + (size_t)nu * 64;
#pragma unroll
            for (int k2 = 0; k2 < 32; ++k2) {
                a0 = fmaf(w[2 * k2], xr[2 * k2], a0);
                a1 = fmaf(w[2 * k2 + 1], xr[2 * k2 + 1], a1);
            }
        }
        Z[(size_t)nu * 64 + lane] = (h16)(a0 + a1);
    }
}

// Per-block LDS histogram over buckets; each edge read once, both directions.
__global__ void hist_kernel(const int* __restrict__ esrc,
                            const int* __restrict__ edst,
                            int* __restrict__ bucketTotal,
                            int* __restrict__ blockBase, int E, int NB) {
    __shared__ int cnt[NBMAX];
    for (int b = threadIdx.x; b < NB; b += blockDim.x) cnt[b] = 0;
    __syncthreads();
    const int chunk = (E + gridDim.x - 1) / gridDim.x;
    const int start = blockIdx.x * chunk;
    const int end = min(start + chunk, E);
    for (int e = start + (int)threadIdx.x; e < end; e += blockDim.x) {
        const int s = esrc[e];
        const int d = edst[e];
        if (s != d) {
            atomicAdd(&cnt[d >> 5], 1);
            atomicAdd(&cnt[s >> 5], 1);
        }
    }
    __syncthreads();
    for (int b = threadIdx.x; b < NB; b += blockDim.x)
        blockBase[(size_t)blockIdx.x * NB + b] = atomicAdd(&bucketTotal[b], cnt[b]);
}

// Exclusive prefix scan, single workgroup of 1024 threads (16 waves).
__global__ void scan_kernel(const int* __restrict__ deg,
                            int* __restrict__ offs, int n) {
    __shared__ int wsum[16];
    __shared__ int s_carry;
    const int tid = threadIdx.x;
    const int lane = tid & 63;
    const int wid = tid >> 6;
    if (tid == 0) s_carry = 0;
    __syncthreads();
    for (int base = 0; base < n; base += 1024) {
        const int i = base + tid;
        const int v = (i < n) ? deg[i] : 0;
        int x = v;
#pragma unroll
        for (int off = 1; off < 64; off <<= 1) {
            int t = __shfl_up(x, off, 64);
            if (lane >= off) x += t;
        }
        if (lane == 63) wsum[wid] = x;
        __syncthreads();
        if (wid == 0) {
            int wv = (lane < 16) ? wsum[lane] : 0;
#pragma unroll
            for (int off = 1; off < 16; off <<= 1) {
                int t = __shfl_up(wv, off, 64);
                if (lane >= off) wv += t;
            }
            if (lane < 16) wsum[lane] = wv;
        }
        __syncthreads();
        const int carry = s_carry;
        const int waveoff = (wid > 0) ? wsum[wid - 1] : 0;
        if (i < n) offs[i] = carry + waveoff + x - v;
        __syncthreads();
        if (tid == 0) s_carry = carry + wsum[15];
        __syncthreads();
    }
}

// Append both directions of each edge into per-bucket per-block sub-segments.
// entry = src(16) | dstlocal(5)<<16 | w_q(11)<<21.
__global__ void binfill_kernel(const int* __restrict__ esrc,
                               const int* __restrict__ edst,
                               const float* __restrict__ ewt,
                               const int* __restrict__ bucketStart,
                               const int* __restrict__ blockBase,
                               unsigned* __restrict__ entries, int E, int NB) {
    __shared__ int cur[NBMAX];
    for (int b = threadIdx.x; b < NB; b += blockDim.x)
        cur[b] = bucketStart[b] + blockBase[(size_t)blockIdx.x * NB + b];
    __syncthreads();
    const int chunk = (E + gridDim.x - 1) / gridDim.x;
    const int start = blockIdx.x * chunk;
    const int end = min(start + chunk, E);
    for (int e = start + (int)threadIdx.x; e < end; e += blockDim.x) {
        const int s = esrc[e];
        const int d = edst[e];
        if (s != d) {
            const unsigned wq =
                (unsigned)fminf(ewt[e] * 2048.f + 0.5f, 2047.f) << 21;
            const int pd = atomicAdd(&cur[d >> 5], 1);
            entries[pd] = (unsigned)s | ((unsigned)(d & 31) << 16) | wq;
            const int ps = atomicAdd(&cur[s >> 5], 1);
            entries[ps] = (unsigned)d | ((unsigned)(s & 31) << 16) | wq;
        }
    }
}

// Block per bucket: counting sort by dstlocal within the bucket's segment.
// Emits dst-sorted entries + per-node begin offsets (nodeBeg[n+1]; globally
// contiguous since buckets are contiguous -> end(node) = nodeBeg[node+1]).
__global__ void sortbucket_kernel(const int* __restrict__ bucketStart,
                                  const int* __restrict__ bucketTotal,
                                  const unsigned* __restrict__ in,
                                  unsigned* __restrict__ out,
                                  int* __restrict__ nodeBeg, int n, int NB) {
    __shared__ int bin[32];
    __shared__ int cur[32];
    const int bkt = blockIdx.x;
    const int beg = bucketStart[bkt];
    const int cnt = bucketTotal[bkt];
    if (threadIdx.x < 32) bin[threadIdx.x] = 0;
    __syncthreads();
    for (int i = threadIdx.x; i < cnt; i += blockDim.x)
        atomicAdd(&bin[(in[beg + i] >> 16) & 31u], 1);
    __syncthreads();
    if (threadIdx.x == 0) {
        int run = 0;
#pragma unroll
        for (int r = 0; r < 32; ++r) { cur[r] = run; run += bin[r]; }
    }
    __syncthreads();
    if (threadIdx.x < 32) {
        const int node = bkt * 32 + (int)threadIdx.x;
        if (node < n) nodeBeg[node] = beg + cur[threadIdx.x];
    }
    if (bkt == NB - 1 && threadIdx.x == 0) nodeBeg[n] = beg + cnt;
    __syncthreads();
    for (int i = threadIdx.x; i < cnt; i += blockDim.x) {
        const unsigned e = in[beg + i];
        const int pos = beg + atomicAdd(&cur[(e >> 16) & 31u], 1);
        out[pos] = e;
    }
}

// Wave per destination node: walk its sorted entry run, register fmax.
// No LDS, no atomics; seed 0 == relu'd max with empty->0.
__global__ void aggregateN_kernel(const int* __restrict__ nodeBeg,
                                  const unsigned* __restrict__ entries,
                                  const h16* __restrict__ Z,
                                  const float* __restrict__ pb,
                                  const float* __restrict__ coefp,
                                  h16* __restrict__ agg, int n) {
    const int lane = threadIdx.x & 63;
    int wave = (int)((blockIdx.x * blockDim.x + threadIdx.x) >> 6);
    const int nwaves = (int)((gridDim.x * blockDim.x) >> 6);
    const float coefq = coefp[0] * (1.f / 2048.f);
    const float pbc = pb[lane];
    for (int d = wave; d < n; d += nwaves) {
        const int du = __builtin_amdgcn_readfirstlane(d);
        const int beg = nodeBeg[du];
        const int end = nodeBeg[du + 1];
        float m0 = 0.f, m1 = 0.f, m2 = 0.f, m3 = 0.f;
        int i = beg;
        for (; i + 4 <= end; i += 4) {
            const unsigned e0 = (unsigned)__builtin_amdgcn_readfirstlane((int)entries[i]);
            const unsigned e1 = (unsigned)__builtin_amdgcn_readfirstlane((int)entries[i + 1]);
            const unsigned e2 = (unsigned)__builtin_amdgcn_readfirstlane((int)entries[i + 2]);
            const unsigned e3 = (unsigned)__builtin_amdgcn_readfirstlane((int)entries[i + 3]);
            const float z0 = (float)Z[(size_t)(e0 & 0xffffu) * 64 + lane];
            const float z1 = (float)Z[(size_t)(e1 & 0xffffu) * 64 + lane];
            const float z2 = (float)Z[(size_t)(e2 & 0xffffu) * 64 + lane];
            const float z3 = (float)Z[(size_t)(e3 & 0xffffu) * 64 + lane];
            m0 = fmaxf(m0, fmaf(fmaf(coefq, (float)(e0 >> 21), 1.f), z0, pbc));
            m1 = fmaxf(m1, fmaf(fmaf(coefq, (float)(e1 >> 21), 1.f), z1, pbc));
            m2 = fmaxf(m2, fmaf(fmaf(coefq, (float)(e2 >> 21), 1.f), z2, pbc));
            m3 = fmaxf(m3, fmaf(fmaf(coefq, (float)(e3 >> 21), 1.f), z3, pbc));
        }
        for (; i < end; ++i) {
            const unsigned e = (unsigned)__builtin_amdgcn_readfirstlane((int)entries[i]);
            const float zv = (float)Z[(size_t)(e & 0xffffu) * 64 + lane];
            m0 = fmaxf(m0, fmaf(fmaf(coefq, (float)(e >> 21), 1.f), zv, pbc));
        }
        agg[(size_t)du * 64 + lane] = (h16)fmaxf(fmaxf(m0, m1), fmaxf(m2, m3));
    }
}

// H1 = relu([X | AGG] @ W.T + b)   (X fp32, AGG fp16, H fp16)
__global__ __launch_bounds__(256, 2)
void fin1_kernel(const float* __restrict__ X,
                 const h16* __restrict__ AGG,
                 const float* __restrict__ W,
                 const float* __restrict__ b,
                 h16* __restrict__ H, int n) {
    const int lane = threadIdx.x & 63;
    int wave = (int)((blockIdx.x * blockDim.x + threadIdx.x) >> 6);
    const int nwaves = (int)((gridDim.x * blockDim.x) >> 6);
    float wx[64], wa[64];
#pragma unroll
    for (int k = 0; k < 64; ++k) wx[k] = W[lane * 128 + k];
#pragma unroll
    for (int k = 0; k < 64; ++k) wa[k] = W[lane * 128 + 64 + k];
#pragma unroll
    for (int k = 0; k < 64; ++k) { PIN(wx[k]); PIN(wa[k]); }
    const float bc = b[lane];
    for (int node = wave; node < n; node += nwaves) {
        const int nu = __builtin_amdgcn_readfirstlane(node);
        const float* __restrict__ xr = X + (size_t)nu * 64;
        const unsigned* __restrict__ ar = (const unsigned*)(AGG + (size_t)nu * 64);
        float a0 = bc, a1 = 0.f, a2 = 0.f, a3 = 0.f;
#pragma unroll
        for (int k2 = 0; k2 < 32; ++k2) {
            a0 = fmaf(wx[2 * k2], xr[2 * k2], a0);
            a1 = fmaf(wx[2 * k2 + 1], xr[2 * k2 + 1], a1);
        }
#pragma unroll
        for (int k2 = 0; k2 < 32; ++k2) {
            HU cv; cv.u = ar[k2];
            a2 = fmaf(wa[2 * k2], (float)cv.h[0], a2);
            a3 = fmaf(wa[2 * k2 + 1], (float)cv.h[1], a3);
        }
        H[(size_t)nu * 64 + lane] = (h16)fmaxf((a0 + a1) + (a2 + a3), 0.f);
    }
}

// Layer-2 fin fused with the head projections: h2 never materialized.
// nodeheads[node] = { ewp.h_s, ewp.h_d, ep.h_s, ep.h_d }
__global__ __launch_bounds__(256, 2)
void fin2_heads_kernel(const h16* __restrict__ X,
                       const h16* __restrict__ AGG,
                       const float* __restrict__ W,
                       const float* __restrict__ b,
                       const float* __restrict__ ewp_w,
                       const float* __restrict__ ep_w,
                       float4* __restrict__ nodeheads, int n) {
    const int lane = threadIdx.x & 63;
    int wave = (int)((blockIdx.x * blockDim.x + threadIdx.x) >> 6);
    const int nwaves = (int)((gridDim.x * blockDim.x) >> 6);
    float wx[64], wa[64];
#pragma unroll
    for (int k = 0; k < 64; ++k) wx[k] = W[lane * 128 + k];
#pragma unroll
    for (int k = 0; k < 64; ++k) wa[k] = W[lane * 128 + 64 + k];
#pragma unroll
    for (int k = 0; k < 64; ++k) { PIN(wx[k]); PIN(wa[k]); }
    const float bc = b[lane];
    const float w1s = ewp_w[lane], w1d = ewp_w[64 + lane];
    const float w2s = ep_w[lane], w2d = ep_w[64 + lane];
    for (int node = wave; node < n; node += nwaves) {
        const int nu = __builtin_amdgcn_readfirstlane(node);
        const unsigned* __restrict__ xr = (const unsigned*)(X + (size_t)nu * 64);
        const unsigned* __restrict__ ar = (const unsigned*)(AGG + (size_t)nu * 64);
        float a0 = bc, a1 = 0.f, a2 = 0.f, a3 = 0.f;
#pragma unroll
        for (int k2 = 0; k2 < 32; ++k2) {
            HU cx; cx.u = xr[k2];
            a0 = fmaf(wx[2 * k2], (float)cx.h[0], a0);
            a1 = fmaf(wx[2 * k2 + 1], (float)cx.h[1], a1);
        }
#pragma unroll
        for (int k2 = 0; k2 < 32; ++k2) {
            HU ca; ca.u = ar[k2];
            a2 = fmaf(wa[2 * k2], (float)ca.h[0], a2);
            a3 = fmaf(wa[2 * k2 + 1], (float)ca.h[1], a3);
        }
        const float h = fmaxf((a0 + a1) + (a2 + a3), 0.f);
        float r1 = w1s * h, r2 = w1d * h, r3 = w2s * h, r4 = w2d * h;
#pragma unroll
        for (int m = 32; m >= 1; m >>= 1) {
            r1 += __shfl_xor(r1, m, 64);
            r2 += __shfl_xor(r2, m, 64);
            r3 += __shfl_xor(r3, m, 64);
            r4 += __shfl_xor(r4, m, 64);
        }
        if (lane == 0) nodeheads[nu] = make_float4(r1, r2, r3, r4);
    }
}

// Thread per prediction edge: 2x16 B gathers from the 0.8 MB per-node table.
__global__ void headsP_kernel(const int* __restrict__ psrc,
                              const int* __restrict__ pdst,
                              const float4* __restrict__ nodeheads,
                              const float* __restrict__ ewp_b,
                              const float* __restrict__ ep_b,
                              float* __restrict__ out, int P) {
    int t = blockIdx.x * blockDim.x + threadIdx.x;
    const int stride = gridDim.x * blockDim.x;
    const float b1 = ewp_b[0], b2 = ep_b[0];
    for (; t < P; t += stride) {
        const float4 qs = nodeheads[psrc[t]];
        const float4 qd = nodeheads[pdst[t]];
        out[t] = fmaxf(qs.x + qd.y + b1, 0.f);
        out[(size_t)P + t] = qs.z + qd.w + b2;
    }
}

extern "C" void kernel_launch(void* const* d_in, const int* in_sizes, int n_in,
                              void* d_out, int out_size, void* d_ws, size_t ws_size,
                              hipStream_t stream) {
    const float* x      = (const float*)d_in[0];
    const int*   pe     = (const int*)d_in[1];
    const int*   me     = (const int*)d_in[2];
    const float* mew    = (const float*)d_in[3];
    const float* coef1  = (const float*)d_in[4];
    const float* p1w    = (const float*)d_in[5];
    const float* p1b    = (const float*)d_in[6];
    const float* f1w    = (const float*)d_in[7];
    const float* f1b    = (const float*)d_in[8];
    const float* coef2  = (const float*)d_in[9];
    const float* p2w    = (const float*)d_in[10];
    const float* p2b    = (const float*)d_in[11];
    const float* f2w    = (const float*)d_in[12];
    const float* f2b    = (const float*)d_in[13];
    const float* ewp_w  = (const float*)d_in[14];
    const float* ewp_b  = (const float*)d_in[15];
    const float* ep_w   = (const float*)d_in[16];
    const float* ep_b   = (const float*)d_in[17];

    const int n = in_sizes[0] / 64;   // 50000 nodes
    const int P = in_sizes[1] / 2;    // 200000 prediction edges
    const int E = in_sizes[2] / 2;    // 800000 message edges
    const int NB = (n + 31) >> 5;     // 1563 buckets of 32 nodes

    // ws layout (~34 MB): nodeheads first for 16 B alignment.
    float4* nodeheads = (float4*)d_ws;                       // n
    h16* z16   = (h16*)(nodeheads + n);                      // n*64
    h16* agg16 = z16 + (size_t)n * 64;                       // n*64
    h16* h1    = agg16 + (size_t)n * 64;                     // n*64
    unsigned* entriesA = (unsigned*)(h1 + (size_t)n * 64);   // 2E (unsorted)
    unsigned* entriesB = entriesA + 2 * (size_t)E;           // 2E (dst-sorted)
    int* bucketTotal = (int*)(entriesB + 2 * (size_t)E);     // NBMAX
    int* bucketStart = bucketTotal + NBMAX;                  // NBMAX
    int* nodeBeg     = bucketStart + NBMAX;                  // n+1
    int* blockBase   = nodeBeg + (n + 1);                    // NFB*NB

    const int* esrc = me;
    const int* edst = me + E;
    const int* psrc = pe;
    const int* pdst = pe + P;

    const dim3 blk(256);
    const int mmGrid = 1024;
    const int agGrid = 2048;   // 8192 waves over 50k nodes
    const int hpGrid = (P + 255) / 256;

    // ---- bucket build + dst-sort (shared by both layers) ----
    hipMemsetAsync(bucketTotal, 0, (size_t)NB * sizeof(int), stream);
    hist_kernel<<<NFB, blk, 0, stream>>>(esrc, edst, bucketTotal, blockBase, E, NB);
    scan_kernel<<<1, 1024, 0, stream>>>(bucketTotal, bucketStart, NB);
    binfill_kernel<<<NFB, blk, 0, stream>>>(esrc, edst, mew, bucketStart,
                                            blockBase, entriesA, E, NB);
    sortbucket_kernel<<<NB, blk, 0, stream>>>(bucketStart, bucketTotal,
                                              entriesA, entriesB, nodeBeg, n, NB);

    // ---- layer 1 ----
    mm64_kernel<false><<<mmGrid, blk, 0, stream>>>(x, p1w, z16, n);
    aggregateN_kernel<<<agGrid, blk, 0, stream>>>(nodeBeg, entriesB, z16,
                                                  p1b, coef1, agg16, n);
    fin1_kernel<<<mmGrid, blk, 0, stream>>>(x, agg16, f1w, f1b, h1, n);

    // ---- layer 2 ----
    mm64_kernel<true><<<mmGrid, blk, 0, stream>>>(h1, p2w, z16, n);
    aggregateN_kernel<<<agGrid, blk, 0, stream>>>(nodeBeg, entriesB, z16,
                                                  p2b, coef2, agg16, n);
    fin2_heads_kernel<<<mmGrid, blk, 0, stream>>>(h1, agg16, f2w, f2b,
                                                  ewp_w, ep_w, nodeheads, n);

    // ---- edge heads ----
    headsP_kernel<<<hpGrid, blk, 0, stream>>>(psrc, pdst, nodeheads,
                                              ewp_b, ep_b, (float*)d_out, P);
}

// Round 10
// 206.673 us; speedup vs baseline: 1.2462x; 1.2462x over previous
//
#include <hip/hip_runtime.h>

// ---------------------------------------------------------------------------
// GraphSAGE (max-pool SAGE x2 + edge heads), fp32 in/out, fp16 intermediates.
// Identity 1: relu((neigh*scale) @ W.T + b) = relu(scale*(neigh@W.T) + b)
//   -> pool matmul per-NODE (50k) not per-EDGE (1.6M).
// Identity 2: max seeded at 0 == relu'd max with empty->0.
// Round 10: R8/R9 showed the wave-per-node vector matmuls are hostage to the
//   register allocator (weights rematerialized from L1 every iteration; 2
//   rounds of PIN/launch_bounds fixes failed). Rewrite all node matmuls with
//   v_mfma_f32_16x16x16_f16: wave per 16-node tile, W held as B-fragments
//   (true MFMA operands), 16-32 MFMAs/tile, streaming-bound.
//   Layouts: A[i][k]: lane=i+16*(k>>2), holds k=4*(lane>>4)+j (j=0..3);
//            B[k][j]: lane=j+16*(k>>2), same k;   [AMD matrix-core docs]
//            D[i][j]: lane=j+16*(i>>2), reg m=i&3 [m89-verified on gfx950].
// ---------------------------------------------------------------------------

typedef _Float16 h16;
typedef __attribute__((ext_vector_type(4))) _Float16 h16x4;
typedef __attribute__((ext_vector_type(4))) float f32x4;
#define MFMA16(a, b, c) __builtin_amdgcn_mfma_f32_16x16x16f16(a, b, c, 0, 0, 0)

#define NBMAX 1600          // buckets of 32 nodes: ceil(50000/32)=1563
#define NFB   128           // blocks for hist/binfill

// x fp32 -> fp16 (once per call; 8 elems/thread)
__global__ void cvt_kernel(const float* __restrict__ X,
                           h16* __restrict__ X16, int n8) {
    int t = blockIdx.x * blockDim.x + threadIdx.x;
    const int stride = gridDim.x * blockDim.x;
    for (int i = t; i < n8; i += stride) {
        const float4 a = ((const float4*)X)[2 * i];
        const float4 b = ((const float4*)X)[2 * i + 1];
        h16x4 lo = {(h16)a.x, (h16)a.y, (h16)a.z, (h16)a.w};
        h16x4 hi = {(h16)b.x, (h16)b.y, (h16)b.z, (h16)b.w};
        ((h16x4*)X16)[2 * i] = lo;
        ((h16x4*)X16)[2 * i + 1] = hi;
    }
}

// Z = X16 @ W^T  (X16:[n,64] fp16, W:[64,64] fp32 row-major, Z fp16, no bias)
// Wave per 16-node tile; W as B-fragments (4 c-tiles x 4 k-steps).
__global__ __launch_bounds__(256, 2)
void mmA_kernel(const h16* __restrict__ X16, const float* __restrict__ W,
                h16* __restrict__ Z, int ntiles) {
    const int lane = threadIdx.x & 63;
    const int c = lane & 15, q = lane >> 4;
    int wave = (int)((blockIdx.x * blockDim.x + threadIdx.x) >> 6);
    const int nwaves = (int)((gridDim.x * blockDim.x) >> 6);
    h16x4 bf[4][4];
#pragma unroll
    for (int ct = 0; ct < 4; ++ct)
#pragma unroll
        for (int ks = 0; ks < 4; ++ks) {
            const float4 w4 = *(const float4*)(W + (ct * 16 + c) * 64 + ks * 16 + q * 4);
            bf[ct][ks] = (h16x4){(h16)w4.x, (h16)w4.y, (h16)w4.z, (h16)w4.w};
        }
    for (int t = wave; t < ntiles; t += nwaves) {
        const int n0 = t * 16;
        const h16* __restrict__ xrow = X16 + (size_t)(n0 + c) * 64 + q * 4;
        h16x4 af[4];
#pragma unroll
        for (int ks = 0; ks < 4; ++ks) af[ks] = *(const h16x4*)(xrow + ks * 16);
        f32x4 acc[4];
#pragma unroll
        for (int ct = 0; ct < 4; ++ct) acc[ct] = (f32x4){0.f, 0.f, 0.f, 0.f};
#pragma unroll
        for (int ct = 0; ct < 4; ++ct)
#pragma unroll
            for (int ks = 0; ks < 4; ++ks)
                acc[ct] = MFMA16(af[ks], bf[ct][ks], acc[ct]);
#pragma unroll
        for (int ct = 0; ct < 4; ++ct)
#pragma unroll
            for (int m = 0; m < 4; ++m)
                Z[(size_t)(n0 + q * 4 + m) * 64 + ct * 16 + c] = (h16)acc[ct][m];
    }
}

// H = relu([XA | XB] @ W^T + b)  (XA,XB:[n,64] fp16; W:[64,128] fp32; H fp16)
__global__ __launch_bounds__(256, 2)
void finA_kernel(const h16* __restrict__ XA, const h16* __restrict__ XB,
                 const float* __restrict__ W, const float* __restrict__ b,
                 h16* __restrict__ H, int ntiles) {
    const int lane = threadIdx.x & 63;
    const int c = lane & 15, q = lane >> 4;
    int wave = (int)((blockIdx.x * blockDim.x + threadIdx.x) >> 6);
    const int nwaves = (int)((gridDim.x * blockDim.x) >> 6);
    h16x4 bf[4][8];
#pragma unroll
    for (int ct = 0; ct < 4; ++ct)
#pragma unroll
        for (int ks = 0; ks < 8; ++ks) {
            const float4 w4 = *(const float4*)(W + (ct * 16 + c) * 128 + ks * 16 + q * 4);
            bf[ct][ks] = (h16x4){(h16)w4.x, (h16)w4.y, (h16)w4.z, (h16)w4.w};
        }
    float bc[4];
#pragma unroll
    for (int ct = 0; ct < 4; ++ct) bc[ct] = b[ct * 16 + c];
    for (int t = wave; t < ntiles; t += nwaves) {
        const int n0 = t * 16;
        const h16* __restrict__ ra = XA + (size_t)(n0 + c) * 64 + q * 4;
        const h16* __restrict__ rb = XB + (size_t)(n0 + c) * 64 + q * 4;
        h16x4 af[8];
#pragma unroll
        for (int ks = 0; ks < 4; ++ks) {
            af[ks] = *(const h16x4*)(ra + ks * 16);
            af[4 + ks] = *(const h16x4*)(rb + ks * 16);
        }
        f32x4 acc[4];
#pragma unroll
        for (int ct = 0; ct < 4; ++ct) acc[ct] = (f32x4){bc[ct], bc[ct], bc[ct], bc[ct]};
#pragma unroll
        for (int ct = 0; ct < 4; ++ct)
#pragma unroll
            for (int ks = 0; ks < 8; ++ks)
                acc[ct] = MFMA16(af[ks], bf[ct][ks], acc[ct]);
#pragma unroll
        for (int ct = 0; ct < 4; ++ct)
#pragma unroll
            for (int m = 0; m < 4; ++m)
                H[(size_t)(n0 + q * 4 + m) * 64 + ct * 16 + c] =
                    (h16)fmaxf(acc[ct][m], 0.f);
    }
}

// Layer-2 fin + head projections fused; h2 never materialized.
// nodeheads[node] = { sum(ewp_s*h), sum(ewp_d*h), sum(ep_s*h), sum(ep_d*h) }
__global__ __launch_bounds__(256, 2)
void fin2A_kernel(const h16* __restrict__ XA, const h16* __restrict__ XB,
                  const float* __restrict__ W, const float* __restrict__ b,
                  const float* __restrict__ ewp_w, const float* __restrict__ ep_w,
                  float4* __restrict__ nodeheads, int ntiles) {
    const int lane = threadIdx.x & 63;
    const int c = lane & 15, q = lane >> 4;
    int wave = (int)((blockIdx.x * blockDim.x + threadIdx.x) >> 6);
    const int nwaves = (int)((gridDim.x * blockDim.x) >> 6);
    h16x4 bf[4][8];
#pragma unroll
    for (int ct = 0; ct < 4; ++ct)
#pragma unroll
        for (int ks = 0; ks < 8; ++ks) {
            const float4 w4 = *(const float4*)(W + (ct * 16 + c) * 128 + ks * 16 + q * 4);
            bf[ct][ks] = (h16x4){(h16)w4.x, (h16)w4.y, (h16)w4.z, (h16)w4.w};
        }
    float bc[4], hw1s[4], hw1d[4], hw2s[4], hw2d[4];
#pragma unroll
    for (int ct = 0; ct < 4; ++ct) {
        bc[ct] = b[ct * 16 + c];
        hw1s[ct] = ewp_w[ct * 16 + c];
        hw1d[ct] = ewp_w[64 + ct * 16 + c];
        hw2s[ct] = ep_w[ct * 16 + c];
        hw2d[ct] = ep_w[64 + ct * 16 + c];
    }
    for (int t = wave; t < ntiles; t += nwaves) {
        const int n0 = t * 16;
        const h16* __restrict__ ra = XA + (size_t)(n0 + c) * 64 + q * 4;
        const h16* __restrict__ rb = XB + (size_t)(n0 + c) * 64 + q * 4;
        h16x4 af[8];
#pragma unroll
        for (int ks = 0; ks < 4; ++ks) {
            af[ks] = *(const h16x4*)(ra + ks * 16);
            af[4 + ks] = *(const h16x4*)(rb + ks * 16);
        }
        f32x4 acc[4];
#pragma unroll
        for (int ct = 0; ct < 4; ++ct) acc[ct] = (f32x4){bc[ct], bc[ct], bc[ct], bc[ct]};
#pragma unroll
        for (int ct = 0; ct < 4; ++ct)
#pragma unroll
            for (int ks = 0; ks < 8; ++ks)
                acc[ct] = MFMA16(af[ks], bf[ct][ks], acc[ct]);
        f32x4 r1 = {0.f, 0.f, 0.f, 0.f}, r2 = r1, r3 = r1, r4 = r1;
#pragma unroll
        for (int ct = 0; ct < 4; ++ct)
#pragma unroll
            for (int m = 0; m < 4; ++m) {
                const float h = fmaxf(acc[ct][m], 0.f);
                r1[m] = fmaf(hw1s[ct], h, r1[m]);
                r2[m] = fmaf(hw1d[ct], h, r2[m]);
                r3[m] = fmaf(hw2s[ct], h, r3[m]);
                r4[m] = fmaf(hw2d[ct], h, r4[m]);
            }
#pragma unroll
        for (int off = 1; off < 16; off <<= 1)
#pragma unroll
            for (int m = 0; m < 4; ++m) {
                r1[m] += __shfl_xor(r1[m], off, 16);
                r2[m] += __shfl_xor(r2[m], off, 16);
                r3[m] += __shfl_xor(r3[m], off, 16);
                r4[m] += __shfl_xor(r4[m], off, 16);
            }
        if (c == 0) {
#pragma unroll
            for (int m = 0; m < 4; ++m)
                nodeheads[n0 + q * 4 + m] =
                    make_float4(r1[m], r2[m], r3[m], r4[m]);
        }
    }
}

// Per-block LDS histogram over buckets; each edge read once, both directions.
__global__ void hist_kernel(const int* __restrict__ esrc,
                            const int* __restrict__ edst,
                            int* __restrict__ bucketTotal,
                            int* __restrict__ blockBase, int E, int NB) {
    __shared__ int cnt[NBMAX];
    for (int b = threadIdx.x; b < NB; b += blockDim.x) cnt[b] = 0;
    __syncthreads();
    const int chunk = (E + gridDim.x - 1) / gridDim.x;
    const int start = blockIdx.x * chunk;
    const int end = min(start + chunk, E);
    for (int e = start + (int)threadIdx.x; e < end; e += blockDim.x) {
        const int s = esrc[e];
        const int d = edst[e];
        if (s != d) {
            atomicAdd(&cnt[d >> 5], 1);
            atomicAdd(&cnt[s >> 5], 1);
        }
    }
    __syncthreads();
    for (int b = threadIdx.x; b < NB; b += blockDim.x)
        blockBase[(size_t)blockIdx.x * NB + b] = atomicAdd(&bucketTotal[b], cnt[b]);
}

// Exclusive prefix scan, single workgroup of 1024 threads (16 waves).
__global__ void scan_kernel(const int* __restrict__ deg,
                            int* __restrict__ offs, int n) {
    __shared__ int wsum[16];
    __shared__ int s_carry;
    const int tid = threadIdx.x;
    const int lane = tid & 63;
    const int wid = tid >> 6;
    if (tid == 0) s_carry = 0;
    __syncthreads();
    for (int base = 0; base < n; base += 1024) {
        const int i = base + tid;
        const int v = (i < n) ? deg[i] : 0;
        int x = v;
#pragma unroll
        for (int off = 1; off < 64; off <<= 1) {
            int t = __shfl_up(x, off, 64);
            if (lane >= off) x += t;
        }
        if (lane == 63) wsum[wid] = x;
        __syncthreads();
        if (wid == 0) {
            int wv = (lane < 16) ? wsum[lane] : 0;
#pragma unroll
            for (int off = 1; off < 16; off <<= 1) {
                int t = __shfl_up(wv, off, 64);
                if (lane >= off) wv += t;
            }
            if (lane < 16) wsum[lane] = wv;
        }
        __syncthreads();
        const int carry = s_carry;
        const int waveoff = (wid > 0) ? wsum[wid - 1] : 0;
        if (i < n) offs[i] = carry + waveoff + x - v;
        __syncthreads();
        if (tid == 0) s_carry = carry + wsum[15];
        __syncthreads();
    }
}

// Append both directions of each edge into per-bucket per-block sub-segments.
// entry = src(16) | dstlocal(5)<<16 | w_q(11)<<21.
__global__ void binfill_kernel(const int* __restrict__ esrc,
                               const int* __restrict__ edst,
                               const float* __restrict__ ewt,
                               const int* __restrict__ bucketStart,
                               const int* __restrict__ blockBase,
                               unsigned* __restrict__ entries, int E, int NB) {
    __shared__ int cur[NBMAX];
    for (int b = threadIdx.x; b < NB; b += blockDim.x)
        cur[b] = bucketStart[b] + blockBase[(size_t)blockIdx.x * NB + b];
    __syncthreads();
    const int chunk = (E + gridDim.x - 1) / gridDim.x;
    const int start = blockIdx.x * chunk;
    const int end = min(start + chunk, E);
    for (int e = start + (int)threadIdx.x; e < end; e += blockDim.x) {
        const int s = esrc[e];
        const int d = edst[e];
        if (s != d) {
            const unsigned wq =
                (unsigned)fminf(ewt[e] * 2048.f + 0.5f, 2047.f) << 21;
            const int pd = atomicAdd(&cur[d >> 5], 1);
            entries[pd] = (unsigned)s | ((unsigned)(d & 31) << 16) | wq;
            const int ps = atomicAdd(&cur[s >> 5], 1);
            entries[ps] = (unsigned)d | ((unsigned)(s & 31) << 16) | wq;
        }
    }
}

// Block per bucket: counting sort by dstlocal within the bucket's segment.
__global__ void sortbucket_kernel(const int* __restrict__ bucketStart,
                                  const int* __restrict__ bucketTotal,
                                  const unsigned* __restrict__ in,
                                  unsigned* __restrict__ out,
                                  int* __restrict__ nodeBeg, int n, int NB) {
    __shared__ int bin[32];
    __shared__ int cur[32];
    const int bkt = blockIdx.x;
    const int beg = bucketStart[bkt];
    const int cnt = bucketTotal[bkt];
    if (threadIdx.x < 32) bin[threadIdx.x] = 0;
    __syncthreads();
    for (int i = threadIdx.x; i < cnt; i += blockDim.x)
        atomicAdd(&bin[(in[beg + i] >> 16) & 31u], 1);
    __syncthreads();
    if (threadIdx.x == 0) {
        int run = 0;
#pragma unroll
        for (int r = 0; r < 32; ++r) { cur[r] = run; run += bin[r]; }
    }
    __syncthreads();
    if (threadIdx.x < 32) {
        const int node = bkt * 32 + (int)threadIdx.x;
        if (node < n) nodeBeg[node] = beg + cur[threadIdx.x];
    }
    if (bkt == NB - 1 && threadIdx.x == 0) nodeBeg[n] = beg + cnt;
    __syncthreads();
    for (int i = threadIdx.x; i < cnt; i += blockDim.x) {
        const unsigned e = in[beg + i];
        const int pos = beg + atomicAdd(&cur[(e >> 16) & 31u], 1);
        out[pos] = e;
    }
}

// Wave per destination node: walk its sorted entry run, register fmax.
__global__ void aggregateN_kernel(const int* __restrict__ nodeBeg,
                                  const unsigned* __restrict__ entries,
                                  const h16* __restrict__ Z,
                                  const float* __restrict__ pb,
                                  const float* __restrict__ coefp,
                                  h16* __restrict__ agg, int n) {
    const int lane = threadIdx.x & 63;
    int wave = (int)((blockIdx.x * blockDim.x + threadIdx.x) >> 6);
    const int nwaves = (int)((gridDim.x * blockDim.x) >> 6);
    const float coefq = coefp[0] * (1.f / 2048.f);
    const float pbc = pb[lane];
    for (int d = wave; d < n; d += nwaves) {
        const int du = __builtin_amdgcn_readfirstlane(d);
        const int beg = nodeBeg[du];
        const int end = nodeBeg[du + 1];
        float m0 = 0.f, m1 = 0.f, m2 = 0.f, m3 = 0.f;
        int i = beg;
        for (; i + 4 <= end; i += 4) {
            const unsigned e0 = (unsigned)__builtin_amdgcn_readfirstlane((int)entries[i]);
            const unsigned e1 = (unsigned)__builtin_amdgcn_readfirstlane((int)entries[i + 1]);
            const unsigned e2 = (unsigned)__builtin_amdgcn_readfirstlane((int)entries[i + 2]);
            const unsigned e3 = (unsigned)__builtin_amdgcn_readfirstlane((int)entries[i + 3]);
            const float z0 = (float)Z[(size_t)(e0 & 0xffffu) * 64 + lane];
            const float z1 = (float)Z[(size_t)(e1 & 0xffffu) * 64 + lane];
            const float z2 = (float)Z[(size_t)(e2 & 0xffffu) * 64 + lane];
            const float z3 = (float)Z[(size_t)(e3 & 0xffffu) * 64 + lane];
            m0 = fmaxf(m0, fmaf(fmaf(coefq, (float)(e0 >> 21), 1.f), z0, pbc));
            m1 = fmaxf(m1, fmaf(fmaf(coefq, (float)(e1 >> 21), 1.f), z1, pbc));
            m2 = fmaxf(m2, fmaf(fmaf(coefq, (float)(e2 >> 21), 1.f), z2, pbc));
            m3 = fmaxf(m3, fmaf(fmaf(coefq, (float)(e3 >> 21), 1.f), z3, pbc));
        }
        for (; i < end; ++i) {
            const unsigned e = (unsigned)__builtin_amdgcn_readfirstlane((int)entries[i]);
            const float zv = (float)Z[(size_t)(e & 0xffffu) * 64 + lane];
            m0 = fmaxf(m0, fmaf(fmaf(coefq, (float)(e >> 21), 1.f), zv, pbc));
        }
        agg[(size_t)du * 64 + lane] = (h16)fmaxf(fmaxf(m0, m1), fmaxf(m2, m3));
    }
}

// Thread per prediction edge: 2x16 B gathers from the 0.8 MB per-node table.
__global__ void headsP_kernel(const int* __restrict__ psrc,
                              const int* __restrict__ pdst,
                              const float4* __restrict__ nodeheads,
                              const float* __restrict__ ewp_b,
                              const float* __restrict__ ep_b,
                              float* __restrict__ out, int P) {
    int t = blockIdx.x * blockDim.x + threadIdx.x;
    const int stride = gridDim.x * blockDim.x;
    const float b1 = ewp_b[0], b2 = ep_b[0];
    for (; t < P; t += stride) {
        const float4 qs = nodeheads[psrc[t]];
        const float4 qd = nodeheads[pdst[t]];
        out[t] = fmaxf(qs.x + qd.y + b1, 0.f);
        out[(size_t)P + t] = qs.z + qd.w + b2;
    }
}

extern "C" void kernel_launch(void* const* d_in, const int* in_sizes, int n_in,
                              void* d_out, int out_size, void* d_ws, size_t ws_size,
                              hipStream_t stream) {
    const float* x      = (const float*)d_in[0];
    const int*   pe     = (const int*)d_in[1];
    const int*   me     = (const int*)d_in[2];
    const float* mew    = (const float*)d_in[3];
    const float* coef1  = (const float*)d_in[4];
    const float* p1w    = (const float*)d_in[5];
    const float* p1b    = (const float*)d_in[6];
    const float* f1w    = (const float*)d_in[7];
    const float* f1b    = (const float*)d_in[8];
    const float* coef2  = (const float*)d_in[9];
    const float* p2w    = (const float*)d_in[10];
    const float* p2b    = (const float*)d_in[11];
    const float* f2w    = (const float*)d_in[12];
    const float* f2b    = (const float*)d_in[13];
    const float* ewp_w  = (const float*)d_in[14];
    const float* ewp_b  = (const float*)d_in[15];
    const float* ep_w   = (const float*)d_in[16];
    const float* ep_b   = (const float*)d_in[17];

    const int n = in_sizes[0] / 64;   // 50000 nodes
    const int P = in_sizes[1] / 2;    // 200000 prediction edges
    const int E = in_sizes[2] / 2;    // 800000 message edges
    const int NB = (n + 31) >> 5;     // 1563 buckets of 32 nodes
    const int ntiles = (n + 15) >> 4; // 3125 node tiles (exact: 50000=16*3125)

    // ws layout (~41 MB): nodeheads first for 16 B alignment.
    float4* nodeheads = (float4*)d_ws;                       // n
    h16* z16   = (h16*)(nodeheads + n);                      // n*64
    h16* agg16 = z16 + (size_t)n * 64;                       // n*64
    h16* h1    = agg16 + (size_t)n * 64;                     // n*64
    h16* x16   = h1 + (size_t)n * 64;                        // n*64
    unsigned* entriesA = (unsigned*)(x16 + (size_t)n * 64);  // 2E (unsorted)
    unsigned* entriesB = entriesA + 2 * (size_t)E;           // 2E (dst-sorted)
    int* bucketTotal = (int*)(entriesB + 2 * (size_t)E);     // NBMAX
    int* bucketStart = bucketTotal + NBMAX;                  // NBMAX
    int* nodeBeg     = bucketStart + NBMAX;                  // n+1
    int* blockBase   = nodeBeg + (n + 1);                    // NFB*NB

    const int* esrc = me;
    const int* edst = me + E;
    const int* psrc = pe;
    const int* pdst = pe + P;

    const dim3 blk(256);
    const int mfGrid = (ntiles + 3) / 4;   // 1 wave per 16-node tile
    const int agGrid = 2048;               // 8192 waves over 50k nodes
    const int hpGrid = (P + 255) / 256;

    // ---- x -> fp16 + bucket build + dst-sort (shared by both layers) ----
    cvt_kernel<<<1024, blk, 0, stream>>>(x, x16, n * 64 / 8);
    hipMemsetAsync(bucketTotal, 0, (size_t)NB * sizeof(int), stream);
    hist_kernel<<<NFB, blk, 0, stream>>>(esrc, edst, bucketTotal, blockBase, E, NB);
    scan_kernel<<<1, 1024, 0, stream>>>(bucketTotal, bucketStart, NB);
    binfill_kernel<<<NFB, blk, 0, stream>>>(esrc, edst, mew, bucketStart,
                                            blockBase, entriesA, E, NB);
    sortbucket_kernel<<<NB, blk, 0, stream>>>(bucketStart, bucketTotal,
                                              entriesA, entriesB, nodeBeg, n, NB);

    // ---- layer 1 ----
    mmA_kernel<<<mfGrid, blk, 0, stream>>>(x16, p1w, z16, ntiles);
    aggregateN_kernel<<<agGrid, blk, 0, stream>>>(nodeBeg, entriesB, z16,
                                                  p1b, coef1, agg16, n);
    finA_kernel<<<mfGrid, blk, 0, stream>>>(x16, agg16, f1w, f1b, h1, ntiles);

    // ---- layer 2 ----
    mmA_kernel<<<mfGrid, blk, 0, stream>>>(h1, p2w, z16, ntiles);
    aggregateN_kernel<<<agGrid, blk, 0, stream>>>(nodeBeg, entriesB, z16,
                                                  p2b, coef2, agg16, n);
    fin2A_kernel<<<mfGrid, blk, 0, stream>>>(h1, agg16, f2w, f2b,
                                             ewp_w, ep_w, nodeheads, ntiles);

    // ---- edge heads ----
    headsP_kernel<<<hpGrid, blk, 0, stream>>>(psrc, pdst, nodeheads,
                                              ewp_b, ep_b, (float*)d_out, P);
}